// Round 6
// baseline (570.989 us; speedup 1.0000x reference)
//
#include <hip/hip_runtime.h>
#include <hip/hip_bf16.h>

#define DDIM 128

typedef float    f32x16 __attribute__((ext_vector_type(16)));
typedef float    f32x4  __attribute__((ext_vector_type(4)));
typedef short    bf16x8 __attribute__((ext_vector_type(8)));
typedef __bf16   bf16x2t __attribute__((ext_vector_type(2)));
typedef unsigned u32x2  __attribute__((ext_vector_type(2)));
typedef unsigned u32x4  __attribute__((ext_vector_type(4)));
typedef unsigned short us4 __attribute__((ext_vector_type(4)));

__device__ __forceinline__ unsigned pkbf(float a, float b) {
    bf16x2t v; v[0] = (__bf16)a; v[1] = (__bf16)b;
    return __builtin_bit_cast(unsigned, v);
}

__device__ __forceinline__ short f2bf16s(float a) {
    __bf16 b = (__bf16)a;
    return __builtin_bit_cast(short, b);
}

__device__ __forceinline__ float bf16tof(unsigned short u) {
    return __builtin_bit_cast(float, ((unsigned)u) << 16);
}

__device__ __forceinline__ bf16x8 cvt8(f32x4 a, f32x4 b) {
    u32x4 u = { pkbf(a[0],a[1]), pkbf(a[2],a[3]), pkbf(b[0],b[1]), pkbf(b[2],b[3]) };
    return __builtin_bit_cast(bf16x8, u);
}

__device__ __forceinline__ void plswap(unsigned &x, unsigned &y) {
    u32x2 r = __builtin_amdgcn_permlane32_swap(x, y, false, false);
    x = r[0]; y = r[1];
}

__device__ __forceinline__ float silu(float x) {
    return x * __builtin_amdgcn_rcpf(1.0f + __expf(-x));
}

// async 16B global->LDS (dest = wave-uniform base + lane*16)
__device__ __forceinline__ void load_lds16(const void* g, void* l) {
    __builtin_amdgcn_global_load_lds(
        (const __attribute__((address_space(1))) void*)g,
        (__attribute__((address_space(3))) void*)l, 16, 0, 0);
}

// ---- kernel 0: FRAGMENT-MAJOR bf16 weights (layout verified R2-R5).
__global__ void prep_weights(const float* __restrict__ we, const float* __restrict__ wsrc,
                             const float* __restrict__ wdst, const float* __restrict__ wout,
                             short* __restrict__ w1frag, short* __restrict__ w2frag) {
    int tid = blockIdx.x * 256 + threadIdx.x;        // 65536 total
    if (tid < 24 * 128 * 16) {
        int k8 = tid & 7;
        int hi = (tid >> 3) & 1;
        int n  = (tid >> 4) & 127;
        int s  = tid >> 11;
        int col = 16 * s + 8 * hi + k8;              // 0..383
        const float* src = (col < 128) ? we : ((col < 256) ? wsrc : wdst);
        w1frag[tid] = f2bf16s(src[n * 128 + (col & 127)]);
    } else {
        int t2 = tid - 24 * 128 * 16;
        int k8 = t2 & 7;
        int hi = (t2 >> 3) & 1;
        int n  = (t2 >> 4) & 127;
        int s  = t2 >> 11;
        int col = 16 * s + 8 * hi + k8;              // 0..127
        w2frag[t2] = f2bf16s(wout[n * 128 + col]);
    }
}

// ---- node-table kernel (verified R5): tbl[row] = feat[row] @ Wseg^T (bf16, no bias).
__global__ __launch_bounds__(256, 4) void node_table(
    const float* __restrict__ feat, const short* __restrict__ w1frag,
    int segoff, short* __restrict__ tbl, int N)
{
    const int tid  = threadIdx.x;
    const int wave = tid >> 6;
    const int lane = tid & 63;
    const int lo   = lane & 31;
    const int hi   = lane >> 5;
    const int base = blockIdx.x * 128 + wave * 32;
    const int row  = base + lo;
    const int rcl  = row < N ? row : N - 1;
    const float* pn = feat + (size_t)rcl * DDIM;
    const int coff  = 8 * hi;
    const int fslot = (lo * 2 + hi) * 8;

    f32x16 acc[4];
#pragma unroll
    for (int t = 0; t < 4; ++t)
#pragma unroll
        for (int r = 0; r < 16; ++r) acc[t][r] = 0.0f;

#pragma unroll
    for (int s = 0; s < 8; ++s) {
        const f32x4* pv = (const f32x4*)(pn + 16 * s + coff);
        f32x4 fa = pv[0], fb = pv[1];
        bf16x8 a = cvt8(fa, fb);
        const short* wb = w1frag + (segoff + s) * 2048 + fslot;
#pragma unroll
        for (int t = 0; t < 4; ++t) {
            bf16x8 w = *(const bf16x8*)(wb + t * 512);
            acc[t] = __builtin_amdgcn_mfma_f32_32x32x16_bf16(a, w, acc[t], 0, 0, 0);
        }
    }

#pragma unroll
    for (int r = 0; r < 16; ++r) {
        const int m = (r & 3) + 8 * (r >> 2) + 4 * hi;
        const int node = base + m;
        if (node < N) {
            short* po = tbl + (size_t)node * DDIM;
#pragma unroll
            for (int t = 0; t < 4; ++t)
                po[32 * t + lo] = f2bf16s(acc[t][r]);
        }
    }
}

// ---- fused edge kernel (table path), R6: efeat staged via global_load_lds.
// Blocks of 128 thr = 2 waves; each wave owns 32 edges + a 16 KB swizzled LDS efeat tile.
__global__ __launch_bounds__(128, 2) void edge_kernel_tab(
    const float* __restrict__ efeat, const short* __restrict__ tsrc,
    const short* __restrict__ tdst, const int* __restrict__ src_idx,
    const int* __restrict__ dst_idx, const float* __restrict__ b0,
    const float* __restrict__ b_out, const float* __restrict__ ln_g,
    const float* __restrict__ ln_b, const short* __restrict__ w1frag,
    const short* __restrict__ w2frag, float* __restrict__ out, int E)
{
    __shared__ __align__(16) char smem[2 * 16384];   // per-wave 32 rows x 512 B, chunk-swizzled

    const int tid  = threadIdx.x;
    const int wave = tid >> 6;
    const int lane = tid & 63;
    const int lo   = lane & 31;
    const int hi   = lane >> 5;
    const int ebase = blockIdx.x * 64 + wave * 32;

    char* ebuf = smem + wave * 16384;

    // ---- stage efeat tile: 16 x 1KB async copies, source chunk pre-swizzled ----
    // LDS[r*512 + 16*c] = efeat[row r][16B chunk (c ^ (r&7))]
#pragma unroll
    for (int k = 0; k < 16; ++k) {
        const int r  = 2 * k + hi;                 // wave-local row 0..31
        const int c  = lo;                         // LDS chunk 0..31
        const int cs = c ^ (r & 7);                // swizzled source chunk
        const int gr  = ebase + r;
        const int grc = gr < E ? gr : E - 1;
        const char* gp = (const char*)(efeat + (size_t)grc * DDIM) + cs * 16;
        load_lds16(gp, ebuf + k * 1024);
    }

    // ---- idx + gather burst (verified R5) ----
    const int erow = ebase + lo;
    const int ecl  = erow < E ? erow : E - 1;
    const int sidx = src_idx[ecl];
    const int didx = dst_idx[ecl];
    const short* prs = tsrc + (size_t)sidx * DDIM;
    const short* prd = tdst + (size_t)didx * DDIM;

    const int poff  = 4 * hi;                 // col sub-offset in transposed D-layout
    const int fslot = (lo * 2 + hi) * 8;      // weight fragment slot (shorts)
    const int xsw   = lo & 7;                 // LDS read swizzle for this lane's row

    us4 tsv[16], tdv[16];
#pragma unroll
    for (int t = 0; t < 4; ++t)
#pragma unroll
        for (int Q = 0; Q < 4; ++Q) {
            const int c = 32 * t + 8 * Q + poff;
            tsv[t * 4 + Q] = *(const us4*)(prs + c);
            tdv[t * 4 + Q] = *(const us4*)(prd + c);
        }

    // ---- GEMM1 (transposed): acc[t] rows = n, cols = edges; init b0 ----
    f32x16 acc[4];
#pragma unroll
    for (int t = 0; t < 4; ++t)
#pragma unroll
        for (int Q = 0; Q < 4; ++Q) {
            f32x4 bq = *(const f32x4*)(b0 + 32 * t + 8 * Q + poff);
            acc[t][4*Q+0] = bq[0]; acc[t][4*Q+1] = bq[1];
            acc[t][4*Q+2] = bq[2]; acc[t][4*Q+3] = bq[3];
        }

    // ensure staged efeat (and gathers) landed before LDS reads
    asm volatile("s_waitcnt vmcnt(0)" ::: "memory");

    const char* rb = ebuf + lo * 512;         // this lane's edge row in LDS
#pragma unroll
    for (int s = 0; s < 8; ++s) {
        const int g0 = 4 * s + 2 * hi;        // global 16B chunk index
        f32x4 fa = *(const f32x4*)(rb + 16 * ((g0    ) ^ xsw));
        f32x4 fb = *(const f32x4*)(rb + 16 * ((g0 + 1) ^ xsw));
        bf16x8 x = cvt8(fa, fb);                     // B-frag: efeat[edge lo][16s+8hi+j]
        const short* wb = w1frag + s * 2048 + fslot; // A-frag: W_e[32t+lo][16s+8hi+j]
#pragma unroll
        for (int t = 0; t < 4; ++t) {
            bf16x8 w = *(const bf16x8*)(wb + t * 512);
            acc[t] = __builtin_amdgcn_mfma_f32_32x32x16_bf16(w, x, acc[t], 0, 0, 0);
        }
    }

    // ---- add gathered table rows (lane-local; c = 32t+8Q+4hi+j) ----
#pragma unroll
    for (int t = 0; t < 4; ++t)
#pragma unroll
        for (int Q = 0; Q < 4; ++Q) {
            us4 a = tsv[t * 4 + Q], d = tdv[t * 4 + Q];
#pragma unroll
            for (int j = 0; j < 4; ++j)
                acc[t][4*Q+j] += bf16tof(a[j]) + bf16tof(d[j]);
        }

    // ---- SiLU + pack to bf16, lane-local ----
    unsigned hbf[4][4][2];
#pragma unroll
    for (int t = 0; t < 4; ++t)
#pragma unroll
        for (int Q = 0; Q < 4; ++Q) {
            float h0 = silu(acc[t][4*Q+0]), h1 = silu(acc[t][4*Q+1]);
            float h2 = silu(acc[t][4*Q+2]), h3 = silu(acc[t][4*Q+3]);
            hbf[t][Q][0] = pkbf(h0, h1);
            hbf[t][Q][1] = pkbf(h2, h3);
        }

    // ---- GEMM2 (straight): y = silu(h) @ W2^T ----
    float bov[4];
#pragma unroll
    for (int tt = 0; tt < 4; ++tt) bov[tt] = b_out[32 * tt + lo];

    f32x16 acc2[4];
#pragma unroll
    for (int tt = 0; tt < 4; ++tt)
#pragma unroll
        for (int r = 0; r < 16; ++r) acc2[tt][r] = bov[tt];

#pragma unroll
    for (int s = 0; s < 8; ++s) {
        const int t  = s >> 1;
        const int q0 = (2 * s) & 3;
        const int q1 = q0 + 1;
        unsigned X0 = hbf[t][q0][0], X1 = hbf[t][q0][1];
        unsigned Y0 = hbf[t][q1][0], Y1 = hbf[t][q1][1];
        plswap(X0, Y0);
        plswap(X1, Y1);
        u32x4 fv = { X0, X1, Y0, Y1 };       // A-frag: h[edge lo][16s+8hi + 0..7]
        bf16x8 hf = __builtin_bit_cast(bf16x8, fv);
        const short* wb = w2frag + s * 2048 + fslot;
#pragma unroll
        for (int tt = 0; tt < 4; ++tt) {
            bf16x8 w = *(const bf16x8*)(wb + tt * 512);
            acc2[tt] = __builtin_amdgcn_mfma_f32_32x32x16_bf16(hf, w, acc2[tt], 0, 0, 0);
        }
    }

    // ---- LayerNorm (butterfly over 32 lanes) + coalesced NT store ----
    float gv[4], bv[4];
#pragma unroll
    for (int tt = 0; tt < 4; ++tt) {
        gv[tt] = ln_g[32 * tt + lo];
        bv[tt] = ln_b[32 * tt + lo];
    }

#pragma unroll
    for (int r = 0; r < 16; ++r) {
        float s1 = acc2[0][r] + acc2[1][r] + acc2[2][r] + acc2[3][r];
        float s2 = acc2[0][r]*acc2[0][r] + acc2[1][r]*acc2[1][r]
                 + acc2[2][r]*acc2[2][r] + acc2[3][r]*acc2[3][r];
#pragma unroll
        for (int msk = 1; msk < 32; msk <<= 1) {
            s1 += __shfl_xor(s1, msk, 64);
            s2 += __shfl_xor(s2, msk, 64);
        }
        const float mu   = s1 * (1.0f / 128.0f);
        const float var  = s2 * (1.0f / 128.0f) - mu * mu;
        const float rstd = rsqrtf(var + 1e-5f);
        const int   m    = (r & 3) + 8 * (r >> 2) + 4 * hi;
        const int   eo   = ebase + m;
        if (eo < E) {
            float* po = out + (size_t)eo * DDIM;
#pragma unroll
            for (int tt = 0; tt < 4; ++tt) {
                float o = (acc2[tt][r] - mu) * rstd * gv[tt] + bv[tt];
                __builtin_nontemporal_store(o, po + 32 * tt + lo);
            }
        }
    }
}

// ---- fallback: full-K kernel (R4-verified), used only if ws can't hold tables ----
__global__ __launch_bounds__(256, 4) void edge_kernel_fullk(
    const float* __restrict__ efeat, const float* __restrict__ src_feat,
    const float* __restrict__ dst_feat, const int* __restrict__ src_idx,
    const int* __restrict__ dst_idx, const float* __restrict__ b0,
    const float* __restrict__ b_out, const float* __restrict__ ln_g,
    const float* __restrict__ ln_b, const short* __restrict__ w1frag,
    const short* __restrict__ w2frag, float* __restrict__ out, int E)
{
    const int tid  = threadIdx.x;
    const int wave = tid >> 6;
    const int lane = tid & 63;
    const int lo   = lane & 31;
    const int hi   = lane >> 5;
    const int ebase = blockIdx.x * 128 + wave * 32;

    const int erow = ebase + lo;
    const int ecl  = erow < E ? erow : E - 1;
    const int sidx = src_idx[ecl];
    const int didx = dst_idx[ecl];
    const float* pe = efeat    + (size_t)ecl  * DDIM;
    const float* ps = src_feat + (size_t)sidx * DDIM;
    const float* pd = dst_feat + (size_t)didx * DDIM;

    const int coff  = 8 * hi;
    const int poff  = 4 * hi;
    const int fslot = (lo * 2 + hi) * 8;

    float bov[4], gv[4], bv[4];
#pragma unroll
    for (int tt = 0; tt < 4; ++tt) {
        int n = 32 * tt + lo;
        bov[tt] = b_out[n]; gv[tt] = ln_g[n]; bv[tt] = ln_b[n];
    }

    f32x16 acc[4];
#pragma unroll
    for (int t = 0; t < 4; ++t)
#pragma unroll
        for (int Q = 0; Q < 4; ++Q) {
            f32x4 bq = *(const f32x4*)(b0 + 32 * t + 8 * Q + poff);
            acc[t][4*Q+0] = bq[0]; acc[t][4*Q+1] = bq[1];
            acc[t][4*Q+2] = bq[2]; acc[t][4*Q+3] = bq[3];
        }

#pragma unroll
    for (int seg = 0; seg < 3; ++seg) {
        const float* p = (seg == 0) ? pe : ((seg == 1) ? ps : pd);
#pragma unroll
        for (int ks = 0; ks < 8; ++ks) {
            const f32x4* pv = (const f32x4*)(p + 16 * ks + coff);
            f32x4 fa, fb;
            if (seg == 0) { fa = __builtin_nontemporal_load(pv); fb = __builtin_nontemporal_load(pv + 1); }
            else          { fa = pv[0];                          fb = pv[1]; }
            bf16x8 x = cvt8(fa, fb);
            const int s = seg * 8 + ks;
            const short* wb = w1frag + s * 2048 + fslot;
#pragma unroll
            for (int t = 0; t < 4; ++t) {
                bf16x8 w = *(const bf16x8*)(wb + t * 512);
                acc[t] = __builtin_amdgcn_mfma_f32_32x32x16_bf16(w, x, acc[t], 0, 0, 0);
            }
        }
    }

    unsigned hbf[4][4][2];
#pragma unroll
    for (int t = 0; t < 4; ++t)
#pragma unroll
        for (int Q = 0; Q < 4; ++Q) {
            float h0 = silu(acc[t][4*Q+0]), h1 = silu(acc[t][4*Q+1]);
            float h2 = silu(acc[t][4*Q+2]), h3 = silu(acc[t][4*Q+3]);
            hbf[t][Q][0] = pkbf(h0, h1);
            hbf[t][Q][1] = pkbf(h2, h3);
        }

    f32x16 acc2[4];
#pragma unroll
    for (int tt = 0; tt < 4; ++tt)
#pragma unroll
        for (int r = 0; r < 16; ++r) acc2[tt][r] = bov[tt];

#pragma unroll
    for (int s = 0; s < 8; ++s) {
        const int t  = s >> 1;
        const int q0 = (2 * s) & 3;
        const int q1 = q0 + 1;
        unsigned X0 = hbf[t][q0][0], X1 = hbf[t][q0][1];
        unsigned Y0 = hbf[t][q1][0], Y1 = hbf[t][q1][1];
        plswap(X0, Y0);
        plswap(X1, Y1);
        u32x4 fv = { X0, X1, Y0, Y1 };
        bf16x8 hf = __builtin_bit_cast(bf16x8, fv);
        const short* wb = w2frag + s * 2048 + fslot;
#pragma unroll
        for (int tt = 0; tt < 4; ++tt) {
            bf16x8 w = *(const bf16x8*)(wb + tt * 512);
            acc2[tt] = __builtin_amdgcn_mfma_f32_32x32x16_bf16(hf, w, acc2[tt], 0, 0, 0);
        }
    }

#pragma unroll
    for (int r = 0; r < 16; ++r) {
        float s1 = acc2[0][r] + acc2[1][r] + acc2[2][r] + acc2[3][r];
        float s2 = acc2[0][r]*acc2[0][r] + acc2[1][r]*acc2[1][r]
                 + acc2[2][r]*acc2[2][r] + acc2[3][r]*acc2[3][r];
#pragma unroll
        for (int msk = 1; msk < 32; msk <<= 1) {
            s1 += __shfl_xor(s1, msk, 64);
            s2 += __shfl_xor(s2, msk, 64);
        }
        const float mu   = s1 * (1.0f / 128.0f);
        const float var  = s2 * (1.0f / 128.0f) - mu * mu;
        const float rstd = rsqrtf(var + 1e-5f);
        const int   m    = (r & 3) + 8 * (r >> 2) + 4 * hi;
        const int   eo   = ebase + m;
        if (eo < E) {
            float* po = out + (size_t)eo * DDIM;
#pragma unroll
            for (int tt = 0; tt < 4; ++tt) {
                float o = (acc2[tt][r] - mu) * rstd * gv[tt] + bv[tt];
                __builtin_nontemporal_store(o, po + 32 * tt + lo);
            }
        }
    }
}

extern "C" void kernel_launch(void* const* d_in, const int* in_sizes, int n_in,
                              void* d_out, int out_size, void* d_ws, size_t ws_size,
                              hipStream_t stream)
{
    const float* efeat    = (const float*)d_in[0];
    const float* src_feat = (const float*)d_in[1];
    const float* dst_feat = (const float*)d_in[2];
    const int*   src_idx  = (const int*)d_in[3];
    const int*   dst_idx  = (const int*)d_in[4];
    const float* w_efeat  = (const float*)d_in[5];
    const float* w_src    = (const float*)d_in[6];
    const float* w_dst    = (const float*)d_in[7];
    const float* b0       = (const float*)d_in[8];
    const float* w_out    = (const float*)d_in[9];
    const float* b_out    = (const float*)d_in[10];
    const float* ln_g     = (const float*)d_in[11];
    const float* ln_b     = (const float*)d_in[12];
    float* out = (float*)d_out;
    const int E    = in_sizes[3];
    const int nsrc = in_sizes[1] / DDIM;
    const int ndst = in_sizes[2] / DDIM;

    short* w1frag = (short*)d_ws;                              // 96 KB
    short* w2frag = (short*)((char*)d_ws + 24 * 128 * 16 * 2); // 32 KB
    const size_t tab_off = 128 * 1024;
    const size_t need = tab_off + ((size_t)nsrc + (size_t)ndst) * DDIM * 2;

    prep_weights<<<256, 256, 0, stream>>>(w_efeat, w_src, w_dst, w_out, w1frag, w2frag);

    if (ws_size >= need) {
        short* tsrc = (short*)((char*)d_ws + tab_off);
        short* tdst = tsrc + (size_t)nsrc * DDIM;
        node_table<<<(nsrc + 127) / 128, 256, 0, stream>>>(src_feat, w1frag, 8,  tsrc, nsrc);
        node_table<<<(ndst + 127) / 128, 256, 0, stream>>>(dst_feat, w1frag, 16, tdst, ndst);
        const int nb2 = (E + 63) / 64;
        edge_kernel_tab<<<nb2, 128, 0, stream>>>(efeat, tsrc, tdst, src_idx, dst_idx,
                                                 b0, b_out, ln_g, ln_b, w1frag, w2frag, out, E);
    } else {
        const int nb = (E + 127) / 128;
        edge_kernel_fullk<<<nb, 256, 0, stream>>>(efeat, src_feat, dst_feat, src_idx, dst_idx,
                                                  b0, b_out, ln_g, ln_b, w1frag, w2frag, out, E);
    }
}

// Round 7
// 490.160 us; speedup vs baseline: 1.1649x; 1.1649x over previous
//
#include <hip/hip_runtime.h>
#include <hip/hip_bf16.h>

#define DDIM 128

typedef float    f32x16 __attribute__((ext_vector_type(16)));
typedef float    f32x4  __attribute__((ext_vector_type(4)));
typedef short    bf16x8 __attribute__((ext_vector_type(8)));
typedef __bf16   bf16x2t __attribute__((ext_vector_type(2)));
typedef unsigned u32x2  __attribute__((ext_vector_type(2)));
typedef unsigned u32x4  __attribute__((ext_vector_type(4)));
typedef unsigned short us4 __attribute__((ext_vector_type(4)));

__device__ __forceinline__ unsigned pkbf(float a, float b) {
    bf16x2t v; v[0] = (__bf16)a; v[1] = (__bf16)b;
    return __builtin_bit_cast(unsigned, v);
}

__device__ __forceinline__ short f2bf16s(float a) {
    __bf16 b = (__bf16)a;
    return __builtin_bit_cast(short, b);
}

__device__ __forceinline__ float bf16tof(unsigned short u) {
    return __builtin_bit_cast(float, ((unsigned)u) << 16);
}

__device__ __forceinline__ bf16x8 cvt8(f32x4 a, f32x4 b) {
    u32x4 u = { pkbf(a[0],a[1]), pkbf(a[2],a[3]), pkbf(b[0],b[1]), pkbf(b[2],b[3]) };
    return __builtin_bit_cast(bf16x8, u);
}

__device__ __forceinline__ void plswap(unsigned &x, unsigned &y) {
    u32x2 r = __builtin_amdgcn_permlane32_swap(x, y, false, false);
    x = r[0]; y = r[1];
}

__device__ __forceinline__ float silu(float x) {
    return x * __builtin_amdgcn_rcpf(1.0f + __expf(-x));
}

// ---- kernel 0: FRAGMENT-MAJOR bf16 weights (layout verified R2-R6).
__global__ void prep_weights(const float* __restrict__ we, const float* __restrict__ wsrc,
                             const float* __restrict__ wdst, const float* __restrict__ wout,
                             short* __restrict__ w1frag, short* __restrict__ w2frag) {
    int tid = blockIdx.x * 256 + threadIdx.x;        // 65536 total
    if (tid < 24 * 128 * 16) {
        int k8 = tid & 7;
        int hi = (tid >> 3) & 1;
        int n  = (tid >> 4) & 127;
        int s  = tid >> 11;
        int col = 16 * s + 8 * hi + k8;              // 0..383
        const float* src = (col < 128) ? we : ((col < 256) ? wsrc : wdst);
        w1frag[tid] = f2bf16s(src[n * 128 + (col & 127)]);
    } else {
        int t2 = tid - 24 * 128 * 16;
        int k8 = t2 & 7;
        int hi = (t2 >> 3) & 1;
        int n  = (t2 >> 4) & 127;
        int s  = t2 >> 11;
        int col = 16 * s + 8 * hi + k8;              // 0..127
        w2frag[t2] = f2bf16s(wout[n * 128 + col]);
    }
}

// ---- node-table kernel (verified R5): tbl[row] = feat[row] @ Wseg^T (bf16, no bias).
__global__ __launch_bounds__(256, 4) void node_table(
    const float* __restrict__ feat, const short* __restrict__ w1frag,
    int segoff, short* __restrict__ tbl, int N)
{
    const int tid  = threadIdx.x;
    const int wave = tid >> 6;
    const int lane = tid & 63;
    const int lo   = lane & 31;
    const int hi   = lane >> 5;
    const int base = blockIdx.x * 128 + wave * 32;
    const int row  = base + lo;
    const int rcl  = row < N ? row : N - 1;
    const float* pn = feat + (size_t)rcl * DDIM;
    const int coff  = 8 * hi;
    const int fslot = (lo * 2 + hi) * 8;

    f32x16 acc[4];
#pragma unroll
    for (int t = 0; t < 4; ++t)
#pragma unroll
        for (int r = 0; r < 16; ++r) acc[t][r] = 0.0f;

#pragma unroll
    for (int s = 0; s < 8; ++s) {
        const f32x4* pv = (const f32x4*)(pn + 16 * s + coff);
        f32x4 fa = pv[0], fb = pv[1];
        bf16x8 a = cvt8(fa, fb);
        const short* wb = w1frag + (segoff + s) * 2048 + fslot;
#pragma unroll
        for (int t = 0; t < 4; ++t) {
            bf16x8 w = *(const bf16x8*)(wb + t * 512);
            acc[t] = __builtin_amdgcn_mfma_f32_32x32x16_bf16(a, w, acc[t], 0, 0, 0);
        }
    }

#pragma unroll
    for (int r = 0; r < 16; ++r) {
        const int m = (r & 3) + 8 * (r >> 2) + 4 * hi;
        const int node = base + m;
        if (node < N) {
            short* po = tbl + (size_t)node * DDIM;
#pragma unroll
            for (int t = 0; t < 4; ++t)
                po[32 * t + lo] = f2bf16s(acc[t][r]);
        }
    }
}

// ---- fused edge kernel (table path), R7: R5 structure + efeat REGISTER BURST.
// All 16 efeat loads issued up-front into dedicated regs (oldest in vmcnt order),
// then 32 gather loads; GEMM1 consumes efeat via counted waits while gathers fly.
__global__ __launch_bounds__(256, 2) void edge_kernel_tab(
    const float* __restrict__ efeat, const short* __restrict__ tsrc,
    const short* __restrict__ tdst, const int* __restrict__ src_idx,
    const int* __restrict__ dst_idx, const float* __restrict__ b0,
    const float* __restrict__ b_out, const float* __restrict__ ln_g,
    const float* __restrict__ ln_b, const short* __restrict__ w1frag,
    const short* __restrict__ w2frag, float* __restrict__ out, int E)
{
    const int tid  = threadIdx.x;
    const int wave = tid >> 6;
    const int lane = tid & 63;
    const int lo   = lane & 31;
    const int hi   = lane >> 5;
    const int ebase = blockIdx.x * 128 + wave * 32;

    const int erow = ebase + lo;              // this lane's edge
    const int ecl  = erow < E ? erow : E - 1;
    const int sidx = src_idx[ecl];
    const int didx = dst_idx[ecl];
    const float* pe = efeat + (size_t)ecl * DDIM;
    const short* prs = tsrc + (size_t)sidx * DDIM;
    const short* prd = tdst + (size_t)didx * DDIM;

    const int coff  = 8 * hi;                 // k sub-offset within a 16-wide K step
    const int poff  = 4 * hi;                 // col sub-offset in transposed D-layout
    const int fslot = (lo * 2 + hi) * 8;      // weight fragment slot (shorts)

    // ---- efeat burst: all 16 loads issued first (oldest in vmcnt queue) ----
    f32x4 fa[8], fb[8];
#pragma unroll
    for (int s = 0; s < 8; ++s) {
        const f32x4* pv = (const f32x4*)(pe + 16 * s + coff);
        fa[s] = __builtin_nontemporal_load(pv);
        fb[s] = __builtin_nontemporal_load(pv + 1);
    }

    // ---- gather burst (newer; consumed after GEMM1) ----
    us4 tsv[16], tdv[16];
#pragma unroll
    for (int t = 0; t < 4; ++t)
#pragma unroll
        for (int Q = 0; Q < 4; ++Q) {
            const int c = 32 * t + 8 * Q + poff;
            tsv[t * 4 + Q] = *(const us4*)(prs + c);
            tdv[t * 4 + Q] = *(const us4*)(prd + c);
        }

    // ---- GEMM1 (transposed): acc[t] rows = n, cols = edges; init b0 ----
    f32x16 acc[4];
#pragma unroll
    for (int t = 0; t < 4; ++t)
#pragma unroll
        for (int Q = 0; Q < 4; ++Q) {
            f32x4 bq = *(const f32x4*)(b0 + 32 * t + 8 * Q + poff);
            acc[t][4*Q+0] = bq[0]; acc[t][4*Q+1] = bq[1];
            acc[t][4*Q+2] = bq[2]; acc[t][4*Q+3] = bq[3];
        }

#pragma unroll
    for (int s = 0; s < 8; ++s) {
        bf16x8 x = cvt8(fa[s], fb[s]);               // B-frag: efeat[edge lo][16s+8hi+j]
        const short* wb = w1frag + s * 2048 + fslot; // A-frag: W_e[32t+lo][16s+8hi+j]
#pragma unroll
        for (int t = 0; t < 4; ++t) {
            bf16x8 w = *(const bf16x8*)(wb + t * 512);
            acc[t] = __builtin_amdgcn_mfma_f32_32x32x16_bf16(w, x, acc[t], 0, 0, 0);
        }
    }

    // ---- add gathered table rows (lane-local; c = 32t+8Q+4hi+j) ----
#pragma unroll
    for (int t = 0; t < 4; ++t)
#pragma unroll
        for (int Q = 0; Q < 4; ++Q) {
            us4 a = tsv[t * 4 + Q], d = tdv[t * 4 + Q];
#pragma unroll
            for (int j = 0; j < 4; ++j)
                acc[t][4*Q+j] += bf16tof(a[j]) + bf16tof(d[j]);
        }

    // ---- SiLU + pack to bf16, lane-local ----
    unsigned hbf[4][4][2];
#pragma unroll
    for (int t = 0; t < 4; ++t)
#pragma unroll
        for (int Q = 0; Q < 4; ++Q) {
            float h0 = silu(acc[t][4*Q+0]), h1 = silu(acc[t][4*Q+1]);
            float h2 = silu(acc[t][4*Q+2]), h3 = silu(acc[t][4*Q+3]);
            hbf[t][Q][0] = pkbf(h0, h1);
            hbf[t][Q][1] = pkbf(h2, h3);
        }

    // ---- GEMM2 (straight): y = silu(h) @ W2^T ----
    float bov[4];
#pragma unroll
    for (int tt = 0; tt < 4; ++tt) bov[tt] = b_out[32 * tt + lo];

    f32x16 acc2[4];
#pragma unroll
    for (int tt = 0; tt < 4; ++tt)
#pragma unroll
        for (int r = 0; r < 16; ++r) acc2[tt][r] = bov[tt];

#pragma unroll
    for (int s = 0; s < 8; ++s) {
        const int t  = s >> 1;
        const int q0 = (2 * s) & 3;
        const int q1 = q0 + 1;
        unsigned X0 = hbf[t][q0][0], X1 = hbf[t][q0][1];
        unsigned Y0 = hbf[t][q1][0], Y1 = hbf[t][q1][1];
        plswap(X0, Y0);
        plswap(X1, Y1);
        u32x4 fv = { X0, X1, Y0, Y1 };       // A-frag: h[edge lo][16s+8hi + 0..7]
        bf16x8 hf = __builtin_bit_cast(bf16x8, fv);
        const short* wb = w2frag + s * 2048 + fslot;
#pragma unroll
        for (int tt = 0; tt < 4; ++tt) {
            bf16x8 w = *(const bf16x8*)(wb + tt * 512);
            acc2[tt] = __builtin_amdgcn_mfma_f32_32x32x16_bf16(hf, w, acc2[tt], 0, 0, 0);
        }
    }

    // ---- LayerNorm (butterfly over 32 lanes) + coalesced NT store ----
    float gv[4], bv[4];
#pragma unroll
    for (int tt = 0; tt < 4; ++tt) {
        gv[tt] = ln_g[32 * tt + lo];
        bv[tt] = ln_b[32 * tt + lo];
    }

#pragma unroll
    for (int r = 0; r < 16; ++r) {
        float s1 = acc2[0][r] + acc2[1][r] + acc2[2][r] + acc2[3][r];
        float s2 = acc2[0][r]*acc2[0][r] + acc2[1][r]*acc2[1][r]
                 + acc2[2][r]*acc2[2][r] + acc2[3][r]*acc2[3][r];
#pragma unroll
        for (int msk = 1; msk < 32; msk <<= 1) {
            s1 += __shfl_xor(s1, msk, 64);
            s2 += __shfl_xor(s2, msk, 64);
        }
        const float mu   = s1 * (1.0f / 128.0f);
        const float var  = s2 * (1.0f / 128.0f) - mu * mu;
        const float rstd = rsqrtf(var + 1e-5f);
        const int   m    = (r & 3) + 8 * (r >> 2) + 4 * hi;
        const int   eo   = ebase + m;
        if (eo < E) {
            float* po = out + (size_t)eo * DDIM;
#pragma unroll
            for (int tt = 0; tt < 4; ++tt) {
                float o = (acc2[tt][r] - mu) * rstd * gv[tt] + bv[tt];
                __builtin_nontemporal_store(o, po + 32 * tt + lo);
            }
        }
    }
}

// ---- fallback: full-K kernel (R4-verified), used only if ws can't hold tables ----
__global__ __launch_bounds__(256, 4) void edge_kernel_fullk(
    const float* __restrict__ efeat, const float* __restrict__ src_feat,
    const float* __restrict__ dst_feat, const int* __restrict__ src_idx,
    const int* __restrict__ dst_idx, const float* __restrict__ b0,
    const float* __restrict__ b_out, const float* __restrict__ ln_g,
    const float* __restrict__ ln_b, const short* __restrict__ w1frag,
    const short* __restrict__ w2frag, float* __restrict__ out, int E)
{
    const int tid  = threadIdx.x;
    const int wave = tid >> 6;
    const int lane = tid & 63;
    const int lo   = lane & 31;
    const int hi   = lane >> 5;
    const int ebase = blockIdx.x * 128 + wave * 32;

    const int erow = ebase + lo;
    const int ecl  = erow < E ? erow : E - 1;
    const int sidx = src_idx[ecl];
    const int didx = dst_idx[ecl];
    const float* pe = efeat    + (size_t)ecl  * DDIM;
    const float* ps = src_feat + (size_t)sidx * DDIM;
    const float* pd = dst_feat + (size_t)didx * DDIM;

    const int coff  = 8 * hi;
    const int poff  = 4 * hi;
    const int fslot = (lo * 2 + hi) * 8;

    float bov[4], gv[4], bv[4];
#pragma unroll
    for (int tt = 0; tt < 4; ++tt) {
        int n = 32 * tt + lo;
        bov[tt] = b_out[n]; gv[tt] = ln_g[n]; bv[tt] = ln_b[n];
    }

    f32x16 acc[4];
#pragma unroll
    for (int t = 0; t < 4; ++t)
#pragma unroll
        for (int Q = 0; Q < 4; ++Q) {
            f32x4 bq = *(const f32x4*)(b0 + 32 * t + 8 * Q + poff);
            acc[t][4*Q+0] = bq[0]; acc[t][4*Q+1] = bq[1];
            acc[t][4*Q+2] = bq[2]; acc[t][4*Q+3] = bq[3];
        }

#pragma unroll
    for (int seg = 0; seg < 3; ++seg) {
        const float* p = (seg == 0) ? pe : ((seg == 1) ? ps : pd);
#pragma unroll
        for (int ks = 0; ks < 8; ++ks) {
            const f32x4* pv = (const f32x4*)(p + 16 * ks + coff);
            f32x4 fa, fb;
            if (seg == 0) { fa = __builtin_nontemporal_load(pv); fb = __builtin_nontemporal_load(pv + 1); }
            else          { fa = pv[0];                          fb = pv[1]; }
            bf16x8 x = cvt8(fa, fb);
            const int s = seg * 8 + ks;
            const short* wb = w1frag + s * 2048 + fslot;
#pragma unroll
            for (int t = 0; t < 4; ++t) {
                bf16x8 w = *(const bf16x8*)(wb + t * 512);
                acc[t] = __builtin_amdgcn_mfma_f32_32x32x16_bf16(w, x, acc[t], 0, 0, 0);
            }
        }
    }

    unsigned hbf[4][4][2];
#pragma unroll
    for (int t = 0; t < 4; ++t)
#pragma unroll
        for (int Q = 0; Q < 4; ++Q) {
            float h0 = silu(acc[t][4*Q+0]), h1 = silu(acc[t][4*Q+1]);
            float h2 = silu(acc[t][4*Q+2]), h3 = silu(acc[t][4*Q+3]);
            hbf[t][Q][0] = pkbf(h0, h1);
            hbf[t][Q][1] = pkbf(h2, h3);
        }

    f32x16 acc2[4];
#pragma unroll
    for (int tt = 0; tt < 4; ++tt)
#pragma unroll
        for (int r = 0; r < 16; ++r) acc2[tt][r] = bov[tt];

#pragma unroll
    for (int s = 0; s < 8; ++s) {
        const int t  = s >> 1;
        const int q0 = (2 * s) & 3;
        const int q1 = q0 + 1;
        unsigned X0 = hbf[t][q0][0], X1 = hbf[t][q0][1];
        unsigned Y0 = hbf[t][q1][0], Y1 = hbf[t][q1][1];
        plswap(X0, Y0);
        plswap(X1, Y1);
        u32x4 fv = { X0, X1, Y0, Y1 };
        bf16x8 hf = __builtin_bit_cast(bf16x8, fv);
        const short* wb = w2frag + s * 2048 + fslot;
#pragma unroll
        for (int tt = 0; tt < 4; ++tt) {
            bf16x8 w = *(const bf16x8*)(wb + tt * 512);
            acc2[tt] = __builtin_amdgcn_mfma_f32_32x32x16_bf16(hf, w, acc2[tt], 0, 0, 0);
        }
    }

#pragma unroll
    for (int r = 0; r < 16; ++r) {
        float s1 = acc2[0][r] + acc2[1][r] + acc2[2][r] + acc2[3][r];
        float s2 = acc2[0][r]*acc2[0][r] + acc2[1][r]*acc2[1][r]
                 + acc2[2][r]*acc2[2][r] + acc2[3][r]*acc2[3][r];
#pragma unroll
        for (int msk = 1; msk < 32; msk <<= 1) {
            s1 += __shfl_xor(s1, msk, 64);
            s2 += __shfl_xor(s2, msk, 64);
        }
        const float mu   = s1 * (1.0f / 128.0f);
        const float var  = s2 * (1.0f / 128.0f) - mu * mu;
        const float rstd = rsqrtf(var + 1e-5f);
        const int   m    = (r & 3) + 8 * (r >> 2) + 4 * hi;
        const int   eo   = ebase + m;
        if (eo < E) {
            float* po = out + (size_t)eo * DDIM;
#pragma unroll
            for (int tt = 0; tt < 4; ++tt) {
                float o = (acc2[tt][r] - mu) * rstd * gv[tt] + bv[tt];
                __builtin_nontemporal_store(o, po + 32 * tt + lo);
            }
        }
    }
}

extern "C" void kernel_launch(void* const* d_in, const int* in_sizes, int n_in,
                              void* d_out, int out_size, void* d_ws, size_t ws_size,
                              hipStream_t stream)
{
    const float* efeat    = (const float*)d_in[0];
    const float* src_feat = (const float*)d_in[1];
    const float* dst_feat = (const float*)d_in[2];
    const int*   src_idx  = (const int*)d_in[3];
    const int*   dst_idx  = (const int*)d_in[4];
    const float* w_efeat  = (const float*)d_in[5];
    const float* w_src    = (const float*)d_in[6];
    const float* w_dst    = (const float*)d_in[7];
    const float* b0       = (const float*)d_in[8];
    const float* w_out    = (const float*)d_in[9];
    const float* b_out    = (const float*)d_in[10];
    const float* ln_g     = (const float*)d_in[11];
    const float* ln_b     = (const float*)d_in[12];
    float* out = (float*)d_out;
    const int E    = in_sizes[3];
    const int nsrc = in_sizes[1] / DDIM;
    const int ndst = in_sizes[2] / DDIM;

    short* w1frag = (short*)d_ws;                              // 96 KB
    short* w2frag = (short*)((char*)d_ws + 24 * 128 * 16 * 2); // 32 KB
    const size_t tab_off = 128 * 1024;
    const size_t need = tab_off + ((size_t)nsrc + (size_t)ndst) * DDIM * 2;

    prep_weights<<<256, 256, 0, stream>>>(w_efeat, w_src, w_dst, w_out, w1frag, w2frag);

    const int nb = (E + 127) / 128;
    if (ws_size >= need) {
        short* tsrc = (short*)((char*)d_ws + tab_off);
        short* tdst = tsrc + (size_t)nsrc * DDIM;
        node_table<<<(nsrc + 127) / 128, 256, 0, stream>>>(src_feat, w1frag, 8,  tsrc, nsrc);
        node_table<<<(ndst + 127) / 128, 256, 0, stream>>>(dst_feat, w1frag, 16, tdst, ndst);
        edge_kernel_tab<<<nb, 256, 0, stream>>>(efeat, tsrc, tdst, src_idx, dst_idx,
                                                b0, b_out, ln_g, ln_b, w1frag, w2frag, out, E);
    } else {
        edge_kernel_fullk<<<nb, 256, 0, stream>>>(efeat, src_feat, dst_feat, src_idx, dst_idx,
                                                  b0, b_out, ln_g, ln_b, w1frag, w2frag, out, E);
    }
}